// Round 1
// baseline (446.212 us; speedup 1.0000x reference)
//
#include <hip/hip_runtime.h>

// SpatialMemoryGrid update:
//  out[b,gh,gw,o, 0:256] = state (blended for the single target cell per (b,o))
//  out[b,gh,gw,o, 256]   = conf' * 0.95  (global decay applied after scatter-set)
//  out[b,gh,gw,o, 257]   = temp' (add temporal_inc at target cell)
//
// Geometry (fixed by the reference):
//   B=4, GH=64, GW=64, N=16, F=256, DECAY=0.95
//   cells = B*GH*GW*N = 262144; out stride per cell = 258 floats (1032 B -> 8B aligned)
//
// Mapping: 256-thread block handles 2 cells; thread t (0..127) within a cell
// moves one float2 of the 256-float state row. Thread t==0 additionally writes
// the (conf, temp) float2 at offset 256.

#define GH 64
#define GW 64
#define NOBJ 16
#define FEAT 256
#define DECAYF 0.95f

__global__ __launch_bounds__(256) void smg_kernel(
    const float* __restrict__ grid_state,      // [B,GH,GW,N,F]
    const float* __restrict__ grid_conf,       // [B,GH,GW,N]
    const float* __restrict__ grid_temp,       // [B,GH,GW,N]
    const float* __restrict__ obj_feat,        // [B,N,F]
    const float* __restrict__ positions,       // [B,N,2]
    const float* __restrict__ occl,            // [B,N]
    float* __restrict__ out)                   // [B,GH,GW,N,258]
{
    const int cell = blockIdx.x * 2 + (threadIdx.x >> 7);   // [0, 262144)
    const int t    = threadIdx.x & 127;                      // float2 index within state row

    const int o  = cell & (NOBJ - 1);
    const int gw = (cell >> 4) & (GW - 1);
    const int gh = (cell >> 10) & (GH - 1);
    const int b  = cell >> 16;
    const int bo = b * NOBJ + o;

    // Recompute this (b,o)'s target cell: pos*63, clip to [0,63] as float, trunc.
    const float px = positions[bo * 2 + 0];
    const float py = positions[bo * 2 + 1];
    const int gwt = (int)fminf(fmaxf(px * (float)(GW - 1), 0.0f), 63.0f);
    const int ght = (int)fminf(fmaxf(py * (float)(GH - 1), 0.0f), 63.0f);
    const bool upd = (gw == gwt) && (gh == ght);

    const float2* __restrict__ sp = (const float2*)grid_state + (size_t)cell * (FEAT / 2);
    float*        __restrict__ ob = out + (size_t)cell * (FEAT + 2);
    float2*       __restrict__ op = (float2*)ob;

    float2 v = sp[t];

    if (upd) {
        const bool  vis   = occl[bo] < 0.5f;
        const float alpha = vis ? 0.8f : 0.3f;
        const float beta  = 1.0f - alpha;
        const float2 w = ((const float2*)obj_feat + (size_t)bo * (FEAT / 2))[t];
        v.x = alpha * w.x + beta * v.x;
        v.y = alpha * w.y + beta * v.y;
    }
    op[t] = v;

    if (t == 0) {
        float c  = grid_conf[cell];
        float tm = grid_temp[cell];
        if (upd) {
            const bool vis = occl[bo] < 0.5f;
            c  = vis ? fminf(1.0f, c * 0.9f + 0.5f) : c * DECAYF;
            tm += vis ? 1.0f : 0.5f;
        }
        float2 ct;
        ct.x = c * DECAYF;   // global decay applied last to every cell
        ct.y = tm;
        ((float2*)(ob + FEAT))[0] = ct;
    }
}

extern "C" void kernel_launch(void* const* d_in, const int* in_sizes, int n_in,
                              void* d_out, int out_size, void* d_ws, size_t ws_size,
                              hipStream_t stream) {
    const float* grid_state = (const float*)d_in[0];
    const float* grid_conf  = (const float*)d_in[1];
    const float* grid_temp  = (const float*)d_in[2];
    const float* obj_feat   = (const float*)d_in[3];
    const float* positions  = (const float*)d_in[4];
    const float* occl       = (const float*)d_in[5];
    float* out = (float*)d_out;

    const int B = in_sizes[5] / NOBJ;                 // 4
    const int cells = B * GH * GW * NOBJ;             // 262144
    const int blocks = cells / 2;                     // 131072 blocks x 256 thr

    smg_kernel<<<blocks, 256, 0, stream>>>(grid_state, grid_conf, grid_temp,
                                           obj_feat, positions, occl, out);
}